// Round 5
// baseline (165.087 us; speedup 1.0000x reference)
//
#include <hip/hip_runtime.h>
#include <hip/hip_bf16.h>

// KAN layer: out = einsum('bik,jik->bj', rbf(x), W) + silu(x)@Wb^T, then LN.
// GEMM view: C[4096,512] = A[4096,8704] * B[512,8704]^T in bf16 MFMA.
//
// R5 structure: LDS pipe was the bottleneck (32KB frag reads + 16KB DMA writes
// per block-iter vs 77 cyc MFMA). Split operand traffic across pipes:
//   - A: materialized in k-slab layout A2[slab][row][kk] (slab=k/32, kk=k&31),
//     staged to LDS via 2x global_load_lds/thread/iter, double-buffered.
//   - B: pre-tiled B2[slab][col][kk]; fragments loaded DIRECTLY from global
//     (one coalesced dwordx4 per frag, L1/L2-hot, no LDS, no barrier dep).
// K = 8192 basis + 512 silu = 272 slabs; z-slice = 34 slabs. Silu cols are
// slabs 256..271, so z=7 needs no special-casing in the gemm.
//
// d_ws layout (113,770,496 B):
//   A2 bf16 [272][4096][32] @ 0        (71,303,168 B)
//   B2 bf16 [272][512][32]  @ 71303168 ( 8,912,896 B)
//   Cp bf16 [8][4096][512]  @ 80216064 (33,554,432 B)  split-K partials

typedef __bf16 bf16x8 __attribute__((ext_vector_type(8)));
typedef __bf16 bf16x4 __attribute__((ext_vector_type(4)));
typedef float  f32x4  __attribute__((ext_vector_type(4)));

#define SPLITS 8
#define NIT 34
#define CPE (4096 * 512)
#define LBUF (128 * 32)        // one A LDS buffer, elements (8 KB)
#define ASLAB 131072           // A2 slab stride, elements (4096*32)
#define BSLAB 16384            // B2 slab stride, elements (512*32)

__device__ __forceinline__ void gll16(const __bf16* g, __bf16* l) {
    __builtin_amdgcn_global_load_lds(
        (const __attribute__((address_space(1))) void*)g,
        (__attribute__((address_space(3))) void*)l, 16, 0, 0);
}

__device__ __forceinline__ float fsilu(float t) {
    return t * __builtin_amdgcn_rcpf(1.0f + __expf(-t));
}

// ---- kernel 1: build A2 (basis + silu) and B2 (W|Wb), all bf16 k-slab -----
// centers linspace(-2,2,16), h=4/15 => z_k = 3.75x + 7.5 - k
__global__ void prep_all(const float* __restrict__ x, const float* __restrict__ W,
                         const float* __restrict__ Wb, __bf16* __restrict__ A2,
                         __bf16* __restrict__ B2) {
    const int blk = blockIdx.x, tid = threadIdx.x;
    if (blk < 4096) {                         // basis: thread -> (b, ip), i=2ip,2ip+1
        int t = blk * 256 + tid;              // 1,048,576 threads
        int b = t & 4095, ip = t >> 12;       // ip 0..255 = slab
        float x0 = x[(size_t)b * 512 + 2 * ip];
        float x1 = x[(size_t)b * 512 + 2 * ip + 1];
        float zb0 = 3.75f * x0 + 7.5f, zb1 = 3.75f * x1 + 7.5f;
        bf16x8 v0, v1, v2, v3;
#pragma unroll
        for (int j = 0; j < 8; ++j) {
            float d0 = zb0 - (float)j;       v0[j] = (__bf16)__expf(-d0 * d0);
            float d1 = zb0 - (float)(j + 8); v1[j] = (__bf16)__expf(-d1 * d1);
            float d2 = zb1 - (float)j;       v2[j] = (__bf16)__expf(-d2 * d2);
            float d3 = zb1 - (float)(j + 8); v3[j] = (__bf16)__expf(-d3 * d3);
        }
        __bf16* p = A2 + ((size_t)ip * 4096 + b) * 32;   // lane-consecutive b -> 64B/lane coalesced
        *(bf16x8*)(p)      = v0;
        *(bf16x8*)(p + 8)  = v1;
        *(bf16x8*)(p + 16) = v2;
        *(bf16x8*)(p + 24) = v3;
    } else if (blk < 4096 + 1024) {           // silu: slabs 256..271
        int t = (blk - 4096) * 256 + tid;     // 262,144 threads
        int b = t >> 6, c = (t & 63) * 8;     // 8 cols per thread
        float4 a0 = *(const float4*)&x[(size_t)b * 512 + c];
        float4 a1 = *(const float4*)&x[(size_t)b * 512 + c + 4];
        bf16x8 v;
        v[0] = (__bf16)fsilu(a0.x); v[1] = (__bf16)fsilu(a0.y);
        v[2] = (__bf16)fsilu(a0.z); v[3] = (__bf16)fsilu(a0.w);
        v[4] = (__bf16)fsilu(a1.x); v[5] = (__bf16)fsilu(a1.y);
        v[6] = (__bf16)fsilu(a1.z); v[7] = (__bf16)fsilu(a1.w);
        *(bf16x8*)(A2 + ((size_t)(256 + (c >> 5)) * 4096 + b) * 32 + (c & 31)) = v;
    } else {                                  // B2: 4 elems per thread
        int t = (blk - 5120) * 256 + tid;     // 1,114,112 threads
        int j = t / 2176;
        int c = (t - j * 2176) * 4;           // global k
        float4 v;
        if (c < 8192) v = *(const float4*)&W[(size_t)j * 8192 + c];
        else          v = *(const float4*)&Wb[(size_t)j * 512 + (c - 8192)];
        bf16x4 o;
        o[0] = (__bf16)v.x; o[1] = (__bf16)v.y; o[2] = (__bf16)v.z; o[3] = (__bf16)v.w;
        *(bf16x4*)(B2 + ((size_t)(c >> 5) * 512 + j) * 32 + (c & 31)) = o;
    }
}

// ---- kernel 2: split-K GEMM, 128x128, A via LDS-DMA dbuf, B via VMEM ------
// A LDS chunk swizzle: 16B chunk (row, qk) at chunk row*4 + (qk ^ ((row>>1)&3))
// -> conflict-free ds_read_b128 (measured 0 conflicts in R2-R4).
__global__ __launch_bounds__(256) void gemm_hyb(const __bf16* __restrict__ A2,
                                                const __bf16* __restrict__ B2,
                                                __bf16* __restrict__ Cp) {
    __shared__ __attribute__((aligned(16))) __bf16 As[2 * LBUF];   // 16 KB total

    const int tid  = threadIdx.x;
    const int wave = tid >> 6, lane = tid & 63;
    const int q    = lane >> 4, r16 = lane & 15;
    const int m0 = blockIdx.x * 128, n0 = blockIdx.y * 128;
    const int bz = blockIdx.z, slab0 = bz * NIT;
    const int wm = wave & 1, wn = wave >> 1;

    // A staging: 512 16B chunks; thread t handles chunks t and t+256.
    const int row0 = tid >> 2, qk0 = (tid & 3) ^ ((row0 >> 1) & 3);
    const int row1 = row0 + 64, qk1 = (tid & 3) ^ ((row1 >> 1) & 3);
    const __bf16* gA0 = A2 + (size_t)slab0 * ASLAB + (size_t)(m0 + row0) * 32 + qk0 * 8;
    const __bf16* gA1 = A2 + (size_t)slab0 * ASLAB + (size_t)(m0 + row1) * 32 + qk1 * 8;
    __bf16* lA0 = &As[tid * 8];
    __bf16* lA1 = &As[(tid + 256) * 8];

    // B fragment base: frag ni at + ni*512, iter at + it*BSLAB. Coalesced:
    // 16 r16-lanes x 4 q-groups = 1 KB contiguous per frag.
    const __bf16* bBase = B2 + (size_t)slab0 * BSLAB
                        + (size_t)(n0 + wn * 64 + r16) * 32 + q * 8;

    f32x4 acc[4][4] = {};
    const int qa = q ^ ((r16 >> 1) & 3);      // de-swizzle for A frag reads
    const int awOff = r16 * 32 + qa * 8 + wm * 64 * 32;

    // prologue: stage A slab 0 into buffer 0
    gll16(gA0, lA0);
    gll16(gA1, lA1);
    __syncthreads();

    for (int it = 0; it < NIT; ++it) {
        // B frags for THIS iter: issued first so the MFMA waitcnt is
        // fine-grained (leaves the 2 newer gll16 DMAs in flight).
        bf16x8 bg[4];
        const __bf16* bp = bBase + (size_t)it * BSLAB;
#pragma unroll
        for (int ni = 0; ni < 4; ++ni) bg[ni] = *(const bf16x8*)(bp + ni * 512);

        // stage A slab it+1 into the other buffer (issue only)
        if (it + 1 < NIT) {
            const size_t go = (size_t)(it + 1) * ASLAB;
            const int sb = ((it + 1) & 1) * LBUF;
            gll16(gA0 + go, &As[sb] + (lA0 - As));
            gll16(gA1 + go, &As[sb] + (lA1 - As));
        }

        // A frags from LDS buffer it&1
        const __bf16* Aw = &As[(it & 1) * LBUF + awOff];
        bf16x8 af[4];
#pragma unroll
        for (int mi = 0; mi < 4; ++mi) af[mi] = *(const bf16x8*)(Aw + mi * 512);

#pragma unroll
        for (int mi = 0; mi < 4; ++mi)
#pragma unroll
            for (int ni = 0; ni < 4; ++ni)
                acc[mi][ni] = __builtin_amdgcn_mfma_f32_16x16x32_bf16(
                    af[mi], bg[ni], acc[mi][ni], 0, 0, 0);

        // one barrier/iter: drains the 2 early-issued DMAs (covered by the
        // 16 MFMAs + 4 VMEM loads above) and guards the A dbuf swap.
        __syncthreads();
    }

    // epilogue: C/D layout col=lane&15, row=(lane>>4)*4+reg; bf16 partials
    __bf16* Cb = Cp + (size_t)bz * CPE;
#pragma unroll
    for (int mi = 0; mi < 4; ++mi) {
        const int row = m0 + wm * 64 + mi * 16 + q * 4;
#pragma unroll
        for (int ni = 0; ni < 4; ++ni) {
            const int col = n0 + wn * 64 + ni * 16 + r16;
#pragma unroll
            for (int r = 0; r < 4; ++r)
                Cb[(size_t)(row + r) * 512 + col] = (__bf16)acc[mi][ni][r];
        }
    }
}

// ---- kernel 3: sum 8 bf16 partials + LayerNorm, one wave per row ----------
__global__ void ln_kernel(const __bf16* __restrict__ Cp, const float* __restrict__ gamma,
                          const float* __restrict__ beta, float* __restrict__ out) {
    const int tid  = threadIdx.x;
    const int wave = tid >> 6, lane = tid & 63;
    const int row  = blockIdx.x * 4 + wave;
    const size_t base = (size_t)row * 512 + lane * 8;

    float v[8] = {};
    float s = 0.f, s2 = 0.f;
#pragma unroll
    for (int z = 0; z < SPLITS; ++z) {
        bf16x8 pv = *(const bf16x8*)(Cp + (size_t)z * CPE + base);
#pragma unroll
        for (int j = 0; j < 8; ++j) v[j] += (float)pv[j];
    }
#pragma unroll
    for (int j = 0; j < 8; ++j) { s += v[j]; s2 += v[j] * v[j]; }
#pragma unroll
    for (int m = 32; m >= 1; m >>= 1) {
        s  += __shfl_xor(s, m);
        s2 += __shfl_xor(s2, m);
    }
    const float mean = s * (1.0f / 512.0f);
    const float var  = s2 * (1.0f / 512.0f) - mean * mean;
    const float rs   = rsqrtf(var + 1e-5f);
    float4 o0, o1;
    const float4 g0 = *(const float4*)&gamma[lane * 8];
    const float4 g1 = *(const float4*)&gamma[lane * 8 + 4];
    const float4 b0 = *(const float4*)&beta[lane * 8];
    const float4 b1 = *(const float4*)&beta[lane * 8 + 4];
    o0.x = (v[0] - mean) * rs * g0.x + b0.x;
    o0.y = (v[1] - mean) * rs * g0.y + b0.y;
    o0.z = (v[2] - mean) * rs * g0.z + b0.z;
    o0.w = (v[3] - mean) * rs * g0.w + b0.w;
    o1.x = (v[4] - mean) * rs * g1.x + b1.x;
    o1.y = (v[5] - mean) * rs * g1.y + b1.y;
    o1.z = (v[6] - mean) * rs * g1.z + b1.z;
    o1.w = (v[7] - mean) * rs * g1.w + b1.w;
    *(float4*)&out[base]     = o0;
    *(float4*)&out[base + 4] = o1;
}

extern "C" void kernel_launch(void* const* d_in, const int* in_sizes, int n_in,
                              void* d_out, int out_size, void* d_ws, size_t ws_size,
                              hipStream_t stream) {
    const float* x     = (const float*)d_in[0];
    const float* W     = (const float*)d_in[1];
    const float* Wb    = (const float*)d_in[2];
    const float* gamma = (const float*)d_in[3];
    const float* beta  = (const float*)d_in[4];
    float* out = (float*)d_out;

    char* ws = (char*)d_ws;
    __bf16* A2 = (__bf16*)ws;                 // 71,303,168 B
    __bf16* B2 = (__bf16*)(ws + 71303168);    //  8,912,896 B
    __bf16* Cp = (__bf16*)(ws + 80216064);    // 33,554,432 B

    prep_all<<<4096 + 1024 + 4352, 256, 0, stream>>>(x, W, Wb, A2, B2);
    dim3 g(32, 4, SPLITS);
    gemm_hyb<<<g, 256, 0, stream>>>(A2, B2, Cp);
    ln_kernel<<<1024, 256, 0, stream>>>(Cp, gamma, beta, out);
}

// Round 6
// 148.405 us; speedup vs baseline: 1.1124x; 1.1124x over previous
//
#include <hip/hip_runtime.h>
#include <hip/hip_bf16.h>

// KAN layer: out = einsum('bik,jik->bj', rbf(x), W) + silu(x)@Wb^T, then LN.
// GEMM view: C[4096,512] = A[4096,8704] * B[512,8704]^T in bf16 MFMA.
//
// R6: serial-sum model says gemm time ≈ HBM(17µs) + LDS(24µs) + MFMA(15µs).
// Attack the LDS term: B fragments load DIRECTLY from global (slab-tiled
// B2[k/32][col][k%32] -> one coalesced dwordx4 per frag, 8.9MB = L2-hot,
// no barrier dep), halving LDS traffic to A-only (24 KB/block-iter).
// R5 tried this but lost occupancy (VGPR 80+64acc=144 > 128 -> 3 blk/CU) and
// broke prep coalescing; R6 pins __launch_bounds__(256,4) and keeps A
// row-major (proven coalesced prep + gll16 staging).
//
// d_ws layout (113,770,496 B):
//   A  bf16 [4096][8704]   @ 0        (71,303,168 B)  row-major [basis|silu]
//   B2 bf16 [272][512][32] @ 71303168 ( 8,912,896 B)  k-slab tiled
//   Cp bf16 [8][4096][512] @ 80216064 (33,554,432 B)  split-K partials

typedef __bf16 bf16x8 __attribute__((ext_vector_type(8)));
typedef __bf16 bf16x4 __attribute__((ext_vector_type(4)));
typedef float  f32x4  __attribute__((ext_vector_type(4)));

#define KT 8704
#define SPLITS 8
#define NIT 34                 // 1088 K per z-slice / BK=32
#define CPE (4096 * 512)
#define LBUF (128 * 32)        // one A LDS buffer (8 KB)
#define BSLAB 16384            // B2 slab stride, elements (512*32)

__device__ __forceinline__ void gll16(const __bf16* g, __bf16* l) {
    __builtin_amdgcn_global_load_lds(
        (const __attribute__((address_space(1))) void*)g,
        (__attribute__((address_space(3))) void*)l, 16, 0, 0);
}

__device__ __forceinline__ float fsilu(float t) {
    return t * __builtin_amdgcn_rcpf(1.0f + __expf(-t));
}

// ---- kernel 1: A (row-major basis|silu) + B2 (slab-tiled W|Wb), bf16 ------
// centers linspace(-2,2,16), h=4/15 => z_k = 3.75x + 7.5 - k
__global__ void prep_all(const float* __restrict__ x, const float* __restrict__ W,
                         const float* __restrict__ Wb, __bf16* __restrict__ A,
                         __bf16* __restrict__ B2) {
    const int blk = blockIdx.x, tid = threadIdx.x;
    if (blk < 8192) {                          // A-part: 1 thread per x elem (coalesced)
        int t = blk * 256 + tid;               // 0 .. 4096*512
        int b = t >> 9;
        int i = t & 511;
        float xv = x[t];
        float zb = 3.75f * xv + 7.5f;
        bf16x8 lo, hi;
#pragma unroll
        for (int k = 0; k < 8; ++k) { float z = zb - (float)k; lo[k]   = (__bf16)__expf(-z * z); }
#pragma unroll
        for (int k = 8; k < 16; ++k){ float z = zb - (float)k; hi[k-8] = (__bf16)__expf(-z * z); }
        size_t base = (size_t)b * KT + (size_t)i * 16;
        *(bf16x8*)(A + base)     = lo;
        *(bf16x8*)(A + base + 8) = hi;
        A[(size_t)b * KT + 8192 + i] = (__bf16)fsilu(xv);
    } else {                                   // B2-part: 4 elems per thread
        int t = (blk - 8192) * 256 + tid;      // 0 .. 512*2176
        int j = t / 2176;
        int c = (t - j * 2176) * 4;            // global k
        float4 v;
        if (c < 8192) v = *(const float4*)&W[(size_t)j * 8192 + c];
        else          v = *(const float4*)&Wb[(size_t)j * 512 + (c - 8192)];
        bf16x4 o;
        o[0] = (__bf16)v.x; o[1] = (__bf16)v.y; o[2] = (__bf16)v.z; o[3] = (__bf16)v.w;
        *(bf16x4*)(B2 + ((size_t)(c >> 5) * 512 + j) * 32 + (c & 31)) = o;
    }
}

// ---- kernel 2: split-K GEMM 128x128: A via LDS-DMA dbuf, B via VMEM -------
// A LDS chunk swizzle: 16B chunk (row, qk) at chunk row*4 + (qk ^ ((row>>1)&3))
// -> conflict-free ds_read_b128 (0 conflicts measured R2-R5).
__global__ __launch_bounds__(256, 4) void gemm_hyb(const __bf16* __restrict__ A,
                                                   const __bf16* __restrict__ B2,
                                                   __bf16* __restrict__ Cp) {
    __shared__ __attribute__((aligned(16))) __bf16 As[2 * LBUF];   // 16 KB

    const int tid  = threadIdx.x;
    const int wave = tid >> 6, lane = tid & 63;
    const int q    = lane >> 4, r16 = lane & 15;
    const int m0 = blockIdx.x * 128, n0 = blockIdx.y * 128;
    const int bz = blockIdx.z, k0 = bz * 1088, slab0 = bz * NIT;
    const int wm = wave & 1, wn = wave >> 1;

    // A staging (row-major source, swizzled LDS dest), 2 chunks/thread
    const int row0 = tid >> 2, qk0 = (tid & 3) ^ ((row0 >> 1) & 3);
    const int row1 = row0 + 64, qk1 = (tid & 3) ^ ((row1 >> 1) & 3);
    const __bf16* gA0 = A + (size_t)(m0 + row0) * KT + k0 + qk0 * 8;
    const __bf16* gA1 = A + (size_t)(m0 + row1) * KT + k0 + qk1 * 8;

    // B fragment base: lanes q*16+r16 tile 1 KB contiguous per frag (dwordx4)
    const __bf16* bBase = B2 + (size_t)slab0 * BSLAB
                        + (size_t)(n0 + wn * 64 + r16) * 32 + q * 8;

    f32x4 acc[4][4] = {};
    const int qa = q ^ ((r16 >> 1) & 3);       // de-swizzle for A frag reads
    const int awOff = (wm * 64 + r16) * 32 + qa * 8;

    // prologue: stage A tile 0 into buffer 0
    gll16(gA0, &As[tid * 8]);
    gll16(gA1, &As[(tid + 256) * 8]);
    __syncthreads();

    for (int it = 0; it < NIT; ++it) {
        // B frags for THIS iter from global (L2-hot, no barrier dep)
        bf16x8 bg[4];
        const __bf16* bp = bBase + (size_t)it * BSLAB;
#pragma unroll
        for (int ni = 0; ni < 4; ++ni) bg[ni] = *(const bf16x8*)(bp + ni * 512);

        // stage A tile it+1 into the other buffer (issue only)
        if (it + 1 < NIT) {
            const int go = (it + 1) * 32;
            const int sb = ((it + 1) & 1) * LBUF;
            gll16(gA0 + go, &As[sb + tid * 8]);
            gll16(gA1 + go, &As[sb + (tid + 256) * 8]);
        }

        // A frags from LDS buffer it&1
        const __bf16* Aw = &As[(it & 1) * LBUF + awOff];
        bf16x8 af[4];
#pragma unroll
        for (int mi = 0; mi < 4; ++mi) af[mi] = *(const bf16x8*)(Aw + mi * 512);

#pragma unroll
        for (int mi = 0; mi < 4; ++mi)
#pragma unroll
            for (int ni = 0; ni < 4; ++ni)
                acc[mi][ni] = __builtin_amdgcn_mfma_f32_16x16x32_bf16(
                    af[mi], bg[ni], acc[mi][ni], 0, 0, 0);

        // one barrier/iter: drains the 2 early-issued DMAs (covered by 16
        // MFMAs + 4 VMEM loads above) and guards the A dbuf swap.
        __syncthreads();
    }

    // epilogue: C/D layout col=lane&15, row=(lane>>4)*4+reg; bf16 partials
    __bf16* Cb = Cp + (size_t)bz * CPE;
#pragma unroll
    for (int mi = 0; mi < 4; ++mi) {
        const int row = m0 + wm * 64 + mi * 16 + q * 4;
#pragma unroll
        for (int ni = 0; ni < 4; ++ni) {
            const int col = n0 + wn * 64 + ni * 16 + r16;
#pragma unroll
            for (int r = 0; r < 4; ++r)
                Cb[(size_t)(row + r) * 512 + col] = (__bf16)acc[mi][ni][r];
        }
    }
}

// ---- kernel 3: sum 8 bf16 partials + LayerNorm, one wave per row ----------
__global__ void ln_kernel(const __bf16* __restrict__ Cp, const float* __restrict__ gamma,
                          const float* __restrict__ beta, float* __restrict__ out) {
    const int tid  = threadIdx.x;
    const int wave = tid >> 6, lane = tid & 63;
    const int row  = blockIdx.x * 4 + wave;
    const size_t base = (size_t)row * 512 + lane * 8;

    float v[8] = {};
    float s = 0.f, s2 = 0.f;
#pragma unroll
    for (int z = 0; z < SPLITS; ++z) {
        bf16x8 pv = *(const bf16x8*)(Cp + (size_t)z * CPE + base);
#pragma unroll
        for (int j = 0; j < 8; ++j) v[j] += (float)pv[j];
    }
#pragma unroll
    for (int j = 0; j < 8; ++j) { s += v[j]; s2 += v[j] * v[j]; }
#pragma unroll
    for (int m = 32; m >= 1; m >>= 1) {
        s  += __shfl_xor(s, m);
        s2 += __shfl_xor(s2, m);
    }
    const float mean = s * (1.0f / 512.0f);
    const float var  = s2 * (1.0f / 512.0f) - mean * mean;
    const float rs   = rsqrtf(var + 1e-5f);
    float4 o0, o1;
    const float4 g0 = *(const float4*)&gamma[lane * 8];
    const float4 g1 = *(const float4*)&gamma[lane * 8 + 4];
    const float4 b0 = *(const float4*)&beta[lane * 8];
    const float4 b1 = *(const float4*)&beta[lane * 8 + 4];
    o0.x = (v[0] - mean) * rs * g0.x + b0.x;
    o0.y = (v[1] - mean) * rs * g0.y + b0.y;
    o0.z = (v[2] - mean) * rs * g0.z + b0.z;
    o0.w = (v[3] - mean) * rs * g0.w + b0.w;
    o1.x = (v[4] - mean) * rs * g1.x + b1.x;
    o1.y = (v[5] - mean) * rs * g1.y + b1.y;
    o1.z = (v[6] - mean) * rs * g1.z + b1.z;
    o1.w = (v[7] - mean) * rs * g1.w + b1.w;
    *(float4*)&out[base]     = o0;
    *(float4*)&out[base + 4] = o1;
}

extern "C" void kernel_launch(void* const* d_in, const int* in_sizes, int n_in,
                              void* d_out, int out_size, void* d_ws, size_t ws_size,
                              hipStream_t stream) {
    const float* x     = (const float*)d_in[0];
    const float* W     = (const float*)d_in[1];
    const float* Wb    = (const float*)d_in[2];
    const float* gamma = (const float*)d_in[3];
    const float* beta  = (const float*)d_in[4];
    float* out = (float*)d_out;

    char* ws = (char*)d_ws;
    __bf16* A  = (__bf16*)ws;                 // 71,303,168 B
    __bf16* B2 = (__bf16*)(ws + 71303168);    //  8,912,896 B
    __bf16* Cp = (__bf16*)(ws + 80216064);    // 33,554,432 B

    prep_all<<<8192 + 4352, 256, 0, stream>>>(x, W, Wb, A, B2);
    dim3 g(32, 4, SPLITS);
    gemm_hyb<<<g, 256, 0, stream>>>(A, B2, Cp);
    ln_kernel<<<1024, 256, 0, stream>>>(Cp, gamma, beta, out);
}